// Round 2
// baseline (703.723 us; speedup 1.0000x reference)
//
#include <hip/hip_runtime.h>
#include <math.h>

#define Bn   8
#define Ln   4096
#define DINn 128
#define Hn   256
#define N2n  8
#define NLn  4

__device__ __forceinline__ float gelu_f(float x) {
    // tanh-approx gelu (JAX default approximate=True)
    float x2 = x * x;
    float inner = 0.7978845608028654f * x * fmaf(0.044715f, x2, 1.0f);
    float e = __expf(2.0f * inner);
    float th = 1.0f - 2.0f / (e + 1.0f);
    return 0.5f * x * (1.0f + th);
}

__device__ __forceinline__ float sigmoid_f(float x) {
    return 1.0f / (1.0f + __expf(-x));
}

// ---------------------------------------------------------------------------
// S4D scan: y = gelu(causal_conv(u, K) + D*u), per (b,h) row, via 8-mode
// diagonal SSM recurrence + wave-parallel chunk scan.
// grid (H/4, B), block 256 (4 waves). Wave v owns h = bx*4+v; lane t owns
// positions l in [t*64, t*64+64).
// ---------------------------------------------------------------------------
__global__ __launch_bounds__(256) void s4_scan_kernel(
    const float* __restrict__ hT,          // (B,H,L) input  (transposed stream)
    float* __restrict__ yT,                // (B,H,L) output (gelu'd)
    const float* __restrict__ log_dt,      // (H)
    const float* __restrict__ log_A_real,  // (H,N2)
    const float* __restrict__ A_imag,      // (H,N2)
    const float* __restrict__ C_re,        // (H,N2)
    const float* __restrict__ C_im,        // (H,N2)
    const float* __restrict__ D_skip)      // (H)
{
    __shared__ float u_lds[4][64][65];     // +1 pad -> 2-way max bank alias (free)
    const int tid = threadIdx.x;
    const int v = tid >> 6;
    const int t = tid & 63;
    const int h = blockIdx.x * 4 + v;
    const int b = blockIdx.y;

    const size_t rowbase = (size_t)(b * Hn + h) * Ln + (size_t)t * 64;
    const float* src = hT + rowbase;
    float* uL = &u_lds[v][t][0];

    // load this lane's 64 contiguous u values (float4, fully coalesced per lane)
    #pragma unroll
    for (int j4 = 0; j4 < 16; ++j4) {
        float4 g = *(const float4*)(src + j4 * 4);
        uL[j4 * 4 + 0] = g.x; uL[j4 * 4 + 1] = g.y;
        uL[j4 * 4 + 2] = g.z; uL[j4 * 4 + 3] = g.w;
    }

    // per-mode params (wave-uniform; computed redundantly per lane)
    float dt = expf(log_dt[h]);
    float wr[N2n], wi[N2n], cr[N2n], ci[N2n];
    #pragma unroll
    for (int n = 0; n < N2n; ++n) {
        float lar = log_A_real[h * N2n + n];
        float aim = A_imag[h * N2n + n];
        float are = -expf(lar);
        float dre = are * dt, dimv = aim * dt;
        float mag = expf(dre);
        float s_, c_;
        sincosf(dimv, &s_, &c_);
        float w_re = mag * c_, w_im = mag * s_;
        wr[n] = w_re; wi[n] = w_im;
        // Ck = (C_re + i C_im) * (w - 1) / A,  A = are + i*aim
        float nre = w_re - 1.0f, nim = w_im;
        float inv = 1.0f / (are * are + aim * aim);
        float tre = (nre * are + nim * aim) * inv;
        float tim = (nim * are - nre * aim) * inv;
        float Cr = C_re[h * N2n + n], Ci = C_im[h * N2n + n];
        cr[n] = Cr * tre - Ci * tim;
        ci[n] = Cr * tim + Ci * tre;
    }
    const float Dsk = D_skip[h];

    // ---- phase 1: local scan (zero init); y_loc + D*u overwrites u in LDS ----
    float sr[N2n], si[N2n];
    #pragma unroll
    for (int n = 0; n < N2n; ++n) { sr[n] = 0.0f; si[n] = 0.0f; }
    #pragma unroll 4
    for (int j = 0; j < 64; ++j) {
        float u = uL[j];
        float acc = 0.0f;
        #pragma unroll
        for (int n = 0; n < N2n; ++n) {
            float nr = fmaf(wr[n], sr[n], fmaf(-wi[n], si[n], u));
            float ni = fmaf(wi[n], sr[n], wr[n] * si[n]);
            sr[n] = nr; si[n] = ni;
            acc = fmaf(cr[n], nr, fmaf(-ci[n], ni, acc));
        }
        uL[j] = fmaf(2.0f, acc, Dsk * u);
    }

    // ---- phase 2: inclusive wave scan of end-states with multiplier w^64 ----
    float mr[N2n], mi[N2n];
    #pragma unroll
    for (int n = 0; n < N2n; ++n) {
        float ar = wr[n], ai = wi[n];
        #pragma unroll
        for (int q = 0; q < 6; ++q) { float nr2 = ar * ar - ai * ai; ai = 2.0f * ar * ai; ar = nr2; }
        mr[n] = ar; mi[n] = ai;   // w^64
    }
    for (int dlt = 1; dlt < 64; dlt <<= 1) {
        #pragma unroll
        for (int n = 0; n < N2n; ++n) {
            float tr = __shfl_up(sr[n], (unsigned)dlt, 64);
            float ti = __shfl_up(si[n], (unsigned)dlt, 64);
            float trz = (t >= dlt) ? tr : 0.0f;
            float tiz = (t >= dlt) ? ti : 0.0f;
            sr[n] = fmaf(mr[n], trz, fmaf(-mi[n], tiz, sr[n]));
            si[n] = fmaf(mr[n], tiz, fmaf(mi[n], trz, si[n]));
        }
        #pragma unroll
        for (int n = 0; n < N2n; ++n) {
            float nr2 = mr[n] * mr[n] - mi[n] * mi[n];
            mi[n] = 2.0f * mr[n] * mi[n];
            mr[n] = nr2;
        }
    }
    // exclusive prefix = incoming state for this lane's chunk
    float pr[N2n], pim[N2n];
    #pragma unroll
    for (int n = 0; n < N2n; ++n) {
        float er = __shfl_up(sr[n], 1u, 64);
        float ei = __shfl_up(si[n], 1u, 64);
        pr[n]  = (t >= 1) ? er : 0.0f;
        pim[n] = (t >= 1) ? ei : 0.0f;
    }

    // ---- phase 3: add correction 2*Re(Ck * w^(j+1) * s_in), gelu, store ----
    float dr2[N2n], di2[N2n];
    #pragma unroll
    for (int n = 0; n < N2n; ++n) { dr2[n] = cr[n]; di2[n] = ci[n]; }
    float* dst = yT + rowbase;
    for (int j4 = 0; j4 < 16; ++j4) {
        float res[4];
        #pragma unroll
        for (int c = 0; c < 4; ++c) {
            float corr = 0.0f;
            #pragma unroll
            for (int n = 0; n < N2n; ++n) {
                float nr2 = dr2[n] * wr[n] - di2[n] * wi[n];
                float ni2 = dr2[n] * wi[n] + di2[n] * wr[n];
                dr2[n] = nr2; di2[n] = ni2;
                corr = fmaf(nr2, pr[n], fmaf(-ni2, pim[n], corr));
            }
            float yv = fmaf(2.0f, corr, uL[j4 * 4 + c]);
            res[c] = gelu_f(yv);
        }
        float4 o; o.x = res[0]; o.y = res[1]; o.z = res[2]; o.w = res[3];
        *(float4*)(dst + j4 * 4) = o;
    }
}

// ---------------------------------------------------------------------------
// fp32 tiled GEMM, 64x64 tile, BK=16, 256 threads, 4x4 microtile.
// KMAJ: Y is (B,H,L) K-major (output of scan). Else Y is (M,K) row-major.
// GLU:  computes a- and g-tiles, out = a*sigmoid(g) + resid.
// Residual is folded into the ts LDS tile BEFORE any global write (resid
// aliases Hout; reads must complete before this block's writes).
// Writes Hout (M,256) row-major AND HTout (B,256,L) transposed.
// ---------------------------------------------------------------------------
template <bool KMAJ, bool GLU>
__global__ __launch_bounds__(256) void gemm_kernel(
    const float* __restrict__ Y,
    const float* __restrict__ Wa,    // rows n0.., K cols
    const float* __restrict__ Wg,    // GLU only
    const float* __restrict__ ba,
    const float* __restrict__ bg,    // GLU only
    const float* resid,              // GLU only (M,256) — ALIASES Hout
    float* Hout,                     // (M,256)
    float* HTout,                    // (B,256,L)
    int K)
{
    __shared__ float ys[16][72];
    __shared__ float was[16][72];
    __shared__ float wgs[16][72];
    __shared__ float ts[64][65];

    const int tid = threadIdx.x;
    const int m0 = blockIdx.x * 64;
    const int n0 = blockIdx.y * 64;
    const int bb = m0 >> 12;          // / 4096
    const int l0 = m0 & (Ln - 1);
    const int tm = tid >> 4, tn = tid & 15;

    float accA[4][4], accG[4][4];
    #pragma unroll
    for (int i = 0; i < 4; ++i)
        #pragma unroll
        for (int j = 0; j < 4; ++j) { accA[i][j] = 0.0f; accG[i][j] = 0.0f; }

    const int nkt = K >> 4;
    for (int kt = 0; kt < nkt; ++kt) {
        const int k0 = kt << 4;
        if constexpr (KMAJ) {
            int kr = tid >> 4, lc = tid & 15;
            float4 g = *(const float4*)(Y + (size_t)(bb * Hn + k0 + kr) * Ln + l0 + lc * 4);
            *(float4*)&ys[kr][lc * 4] = g;
        } else {
            int mr_ = tid >> 2, kc = tid & 3;
            float4 g = *(const float4*)(Y + (size_t)(m0 + mr_) * K + k0 + kc * 4);
            ys[kc * 4 + 0][mr_] = g.x; ys[kc * 4 + 1][mr_] = g.y;
            ys[kc * 4 + 2][mr_] = g.z; ys[kc * 4 + 3][mr_] = g.w;
        }
        {
            int nr_ = tid >> 2, kc = tid & 3;
            float4 g = *(const float4*)(Wa + (size_t)(n0 + nr_) * K + k0 + kc * 4);
            was[kc * 4 + 0][nr_] = g.x; was[kc * 4 + 1][nr_] = g.y;
            was[kc * 4 + 2][nr_] = g.z; was[kc * 4 + 3][nr_] = g.w;
            if constexpr (GLU) {
                float4 g2 = *(const float4*)(Wg + (size_t)(n0 + nr_) * K + k0 + kc * 4);
                wgs[kc * 4 + 0][nr_] = g2.x; wgs[kc * 4 + 1][nr_] = g2.y;
                wgs[kc * 4 + 2][nr_] = g2.z; wgs[kc * 4 + 3][nr_] = g2.w;
            }
        }
        __syncthreads();
        #pragma unroll
        for (int kk = 0; kk < 16; ++kk) {
            float4 av  = *(float4*)&ys[kk][tm * 4];
            float4 bav = *(float4*)&was[kk][tn * 4];
            float a_[4]  = { av.x, av.y, av.z, av.w };
            float ba_[4] = { bav.x, bav.y, bav.z, bav.w };
            if constexpr (GLU) {
                float4 bgv = *(float4*)&wgs[kk][tn * 4];
                float bg_[4] = { bgv.x, bgv.y, bgv.z, bgv.w };
                #pragma unroll
                for (int i = 0; i < 4; ++i)
                    #pragma unroll
                    for (int j = 0; j < 4; ++j) {
                        accA[i][j] = fmaf(a_[i], ba_[j], accA[i][j]);
                        accG[i][j] = fmaf(a_[i], bg_[j], accG[i][j]);
                    }
            } else {
                #pragma unroll
                for (int i = 0; i < 4; ++i)
                    #pragma unroll
                    for (int j = 0; j < 4; ++j)
                        accA[i][j] = fmaf(a_[i], ba_[j], accA[i][j]);
            }
        }
        __syncthreads();
    }

    // epilogue: bias (+GLU +residual) -> ts[n][m].  Residual is READ here,
    // before any global write by this block; every (m,n) is block-owned.
    float bA[4], bG[4];
    #pragma unroll
    for (int j = 0; j < 4; ++j) {
        bA[j] = ba[n0 + tn * 4 + j];
        if constexpr (GLU) bG[j] = bg[n0 + tn * 4 + j];
    }
    #pragma unroll
    for (int i = 0; i < 4; ++i) {
        float4 r;
        if constexpr (GLU)
            r = *(const float4*)(resid + (size_t)(m0 + tm * 4 + i) * Hn + n0 + tn * 4);
        float rr[4] = { r.x, r.y, r.z, r.w };
        #pragma unroll
        for (int j = 0; j < 4; ++j) {
            float va = accA[i][j] + bA[j];
            float o;
            if constexpr (GLU) o = va * sigmoid_f(accG[i][j] + bG[j]) + rr[j];
            else               o = va;
            ts[tn * 4 + j][tm * 4 + i] = o;
        }
    }
    __syncthreads();

    // coalesced write of Hout (row-major) — values come ONLY from ts
    #pragma unroll
    for (int it = 0; it < 4; ++it) {
        int idx = tid + it * 256;
        int mr_ = idx >> 4, pc = idx & 15;
        float4 o;
        o.x = ts[pc * 4 + 0][mr_]; o.y = ts[pc * 4 + 1][mr_];
        o.z = ts[pc * 4 + 2][mr_]; o.w = ts[pc * 4 + 3][mr_];
        *(float4*)(Hout + (size_t)(m0 + mr_) * Hn + n0 + pc * 4) = o;
    }
    // coalesced write of HTout (B,256,L) — values come ONLY from ts
    #pragma unroll
    for (int it = 0; it < 4; ++it) {
        int idx = tid + it * 256;
        int nr_ = idx >> 4, lc = idx & 15;
        float4 o;
        o.x = ts[nr_][lc * 4 + 0]; o.y = ts[nr_][lc * 4 + 1];
        o.z = ts[nr_][lc * 4 + 2]; o.w = ts[nr_][lc * 4 + 3];
        *(float4*)(HTout + (size_t)(bb * Hn + n0 + nr_) * Ln + l0 + lc * 4) = o;
    }
}

extern "C" void kernel_launch(void* const* d_in, const int* in_sizes, int n_in,
                              void* d_out, int out_size, void* d_ws, size_t ws_size,
                              hipStream_t stream) {
    (void)in_sizes; (void)n_in; (void)out_size; (void)ws_size;
    const float* x          = (const float*)d_in[0];
    const float* enc_w      = (const float*)d_in[1];
    const float* enc_b      = (const float*)d_in[2];
    const float* log_dt     = (const float*)d_in[3];
    const float* log_A_real = (const float*)d_in[4];
    const float* A_imag     = (const float*)d_in[5];
    const float* C_re       = (const float*)d_in[6];
    const float* C_im       = (const float*)d_in[7];
    const float* D_skip     = (const float*)d_in[8];
    const float* out_w      = (const float*)d_in[9];
    const float* out_b      = (const float*)d_in[10];

    float* h  = (float*)d_out;                      // residual stream (B,L,H)
    float* hT = (float*)d_ws;                       // (B,H,L)
    float* yT = hT + (size_t)Bn * Hn * Ln;          // (B,H,L)

    const dim3 gg(512, 4), gb(256);

    // encoder: h = x @ enc_w.T + enc_b   (writes h and hT)
    gemm_kernel<false, false><<<gg, gb, 0, stream>>>(
        x, enc_w, nullptr, enc_b, nullptr, nullptr, h, hT, DINn);

    for (int i = 0; i < NLn; ++i) {
        s4_scan_kernel<<<dim3(Hn / 4, Bn), 256, 0, stream>>>(
            hT, yT,
            log_dt + (size_t)i * Hn,
            log_A_real + (size_t)i * Hn * N2n,
            A_imag + (size_t)i * Hn * N2n,
            C_re + (size_t)i * Hn * N2n,
            C_im + (size_t)i * Hn * N2n,
            D_skip + (size_t)i * Hn);

        const float* wlay = out_w + (size_t)i * 2 * Hn * Hn;
        gemm_kernel<true, true><<<gg, gb, 0, stream>>>(
            yT, wlay, wlay + (size_t)Hn * Hn,
            out_b + (size_t)i * 2 * Hn, out_b + (size_t)i * 2 * Hn + Hn,
            h, h, hT, Hn);
    }
}

// Round 3
// 373.885 us; speedup vs baseline: 1.8822x; 1.8822x over previous
//
#include <hip/hip_runtime.h>
#include <hip/hip_bf16.h>
#include <math.h>

#define Bn   8
#define Ln   4096
#define DINn 128
#define Hn   256
#define N2n  8
#define NLn  4

typedef __attribute__((ext_vector_type(4))) float f32x4;
typedef __attribute__((ext_vector_type(8))) short bf16x8;

__device__ __forceinline__ float gelu_f(float x) {
    float x2 = x * x;
    float inner = 0.7978845608028654f * x * fmaf(0.044715f, x2, 1.0f);
    float e = __expf(2.0f * inner);
    float th = 1.0f - 2.0f / (e + 1.0f);
    return 0.5f * x * (1.0f + th);
}

__device__ __forceinline__ float sigmoid_f(float x) {
    return 1.0f / (1.0f + __expf(-x));
}

__device__ __forceinline__ unsigned short f2bf(float f) {
    union { __hip_bfloat16 b; unsigned short u; } cv;
    cv.b = __float2bfloat16(f);
    return cv.u;
}

__device__ __forceinline__ uint4 pack8(float4 a, float4 b) {
    uint4 v;
    v.x = (unsigned)f2bf(a.x) | ((unsigned)f2bf(a.y) << 16);
    v.y = (unsigned)f2bf(a.z) | ((unsigned)f2bf(a.w) << 16);
    v.z = (unsigned)f2bf(b.x) | ((unsigned)f2bf(b.y) << 16);
    v.w = (unsigned)f2bf(b.z) | ((unsigned)f2bf(b.w) << 16);
    return v;
}

// ---------------------------------------------------------------------------
// S4D scan (unchanged math): y = gelu(conv(u,K) + D*u); output bf16 (B,H,L).
// grid (H/4, B), block 256 (4 waves); wave v -> h row, lane t -> l-chunk of 64.
// ---------------------------------------------------------------------------
__global__ __launch_bounds__(256) void s4_scan_kernel(
    const float* __restrict__ hT,          // (B,H,L) f32
    unsigned short* __restrict__ yT,       // (B,H,L) bf16 out
    const float* __restrict__ log_dt,
    const float* __restrict__ log_A_real,
    const float* __restrict__ A_imag,
    const float* __restrict__ C_re,
    const float* __restrict__ C_im,
    const float* __restrict__ D_skip)
{
    __shared__ float u_lds[4][64][65];
    const int tid = threadIdx.x;
    const int v = tid >> 6;
    const int t = tid & 63;
    const int h = blockIdx.x * 4 + v;
    const int b = blockIdx.y;

    const size_t rowbase = (size_t)(b * Hn + h) * Ln + (size_t)t * 64;
    const float* src = hT + rowbase;
    float* uL = &u_lds[v][t][0];

    #pragma unroll
    for (int j4 = 0; j4 < 16; ++j4) {
        float4 g = *(const float4*)(src + j4 * 4);
        uL[j4 * 4 + 0] = g.x; uL[j4 * 4 + 1] = g.y;
        uL[j4 * 4 + 2] = g.z; uL[j4 * 4 + 3] = g.w;
    }

    float dt = expf(log_dt[h]);
    float wr[N2n], wi[N2n], cr[N2n], ci[N2n];
    #pragma unroll
    for (int n = 0; n < N2n; ++n) {
        float lar = log_A_real[h * N2n + n];
        float aim = A_imag[h * N2n + n];
        float are = -expf(lar);
        float dre = are * dt, dimv = aim * dt;
        float mag = expf(dre);
        float s_, c_;
        sincosf(dimv, &s_, &c_);
        float w_re = mag * c_, w_im = mag * s_;
        wr[n] = w_re; wi[n] = w_im;
        float nre = w_re - 1.0f, nim = w_im;
        float inv = 1.0f / (are * are + aim * aim);
        float tre = (nre * are + nim * aim) * inv;
        float tim = (nim * are - nre * aim) * inv;
        float Cr = C_re[h * N2n + n], Ci = C_im[h * N2n + n];
        cr[n] = Cr * tre - Ci * tim;
        ci[n] = Cr * tim + Ci * tre;
    }
    const float Dsk = D_skip[h];

    float sr[N2n], si[N2n];
    #pragma unroll
    for (int n = 0; n < N2n; ++n) { sr[n] = 0.0f; si[n] = 0.0f; }
    #pragma unroll 4
    for (int j = 0; j < 64; ++j) {
        float u = uL[j];
        float acc = 0.0f;
        #pragma unroll
        for (int n = 0; n < N2n; ++n) {
            float nr = fmaf(wr[n], sr[n], fmaf(-wi[n], si[n], u));
            float ni = fmaf(wi[n], sr[n], wr[n] * si[n]);
            sr[n] = nr; si[n] = ni;
            acc = fmaf(cr[n], nr, fmaf(-ci[n], ni, acc));
        }
        uL[j] = fmaf(2.0f, acc, Dsk * u);
    }

    float mr[N2n], mi[N2n];
    #pragma unroll
    for (int n = 0; n < N2n; ++n) {
        float ar = wr[n], ai = wi[n];
        #pragma unroll
        for (int q = 0; q < 6; ++q) { float nr2 = ar * ar - ai * ai; ai = 2.0f * ar * ai; ar = nr2; }
        mr[n] = ar; mi[n] = ai;
    }
    for (int dlt = 1; dlt < 64; dlt <<= 1) {
        #pragma unroll
        for (int n = 0; n < N2n; ++n) {
            float tr = __shfl_up(sr[n], (unsigned)dlt, 64);
            float ti = __shfl_up(si[n], (unsigned)dlt, 64);
            float trz = (t >= dlt) ? tr : 0.0f;
            float tiz = (t >= dlt) ? ti : 0.0f;
            sr[n] = fmaf(mr[n], trz, fmaf(-mi[n], tiz, sr[n]));
            si[n] = fmaf(mr[n], tiz, fmaf(mi[n], trz, si[n]));
        }
        #pragma unroll
        for (int n = 0; n < N2n; ++n) {
            float nr2 = mr[n] * mr[n] - mi[n] * mi[n];
            mi[n] = 2.0f * mr[n] * mi[n];
            mr[n] = nr2;
        }
    }
    float pr[N2n], pim[N2n];
    #pragma unroll
    for (int n = 0; n < N2n; ++n) {
        float er = __shfl_up(sr[n], 1u, 64);
        float ei = __shfl_up(si[n], 1u, 64);
        pr[n]  = (t >= 1) ? er : 0.0f;
        pim[n] = (t >= 1) ? ei : 0.0f;
    }

    float dr2[N2n], di2[N2n];
    #pragma unroll
    for (int n = 0; n < N2n; ++n) { dr2[n] = cr[n]; di2[n] = ci[n]; }
    unsigned short* dst = yT + rowbase;
    for (int j8 = 0; j8 < 8; ++j8) {
        unsigned short rs[8];
        #pragma unroll
        for (int c = 0; c < 8; ++c) {
            float corr = 0.0f;
            #pragma unroll
            for (int n = 0; n < N2n; ++n) {
                float nr2 = dr2[n] * wr[n] - di2[n] * wi[n];
                float ni2 = dr2[n] * wi[n] + di2[n] * wr[n];
                dr2[n] = nr2; di2[n] = ni2;
                corr = fmaf(nr2, pr[n], fmaf(-ni2, pim[n], corr));
            }
            float yv = fmaf(2.0f, corr, uL[j8 * 8 + c]);
            rs[c] = f2bf(gelu_f(yv));
        }
        uint4 o;
        o.x = (unsigned)rs[0] | ((unsigned)rs[1] << 16);
        o.y = (unsigned)rs[2] | ((unsigned)rs[3] << 16);
        o.z = (unsigned)rs[4] | ((unsigned)rs[5] << 16);
        o.w = (unsigned)rs[6] | ((unsigned)rs[7] << 16);
        *(uint4*)(dst + j8 * 8) = o;
    }
}

// ---------------------------------------------------------------------------
// t32: h (b, 4096, 256) f32 -> hT (b, 256, 4096) f32.  64x64 LDS tile.
// ---------------------------------------------------------------------------
__global__ __launch_bounds__(256) void t32_kernel(
    const float* __restrict__ src, float* __restrict__ dst)
{
    __shared__ float tl[64 * 65];
    const int tid = threadIdx.x;
    const int l0 = blockIdx.x * 64, h0 = blockIdx.y * 64, b = blockIdx.z;
    #pragma unroll
    for (int it = 0; it < 4; ++it) {
        int idx = it * 256 + tid; int r = idx >> 4, c4 = idx & 15;
        float4 g = *(const float4*)(src + ((size_t)(b * Ln + l0 + r)) * Hn + h0 + c4 * 4);
        tl[r * 65 + c4 * 4 + 0] = g.x; tl[r * 65 + c4 * 4 + 1] = g.y;
        tl[r * 65 + c4 * 4 + 2] = g.z; tl[r * 65 + c4 * 4 + 3] = g.w;
    }
    __syncthreads();
    #pragma unroll
    for (int it = 0; it < 4; ++it) {
        int idx = it * 256 + tid; int lc = idx & 15, hr = idx >> 4;
        float4 o;
        o.x = tl[(lc * 4 + 0) * 65 + hr];
        o.y = tl[(lc * 4 + 1) * 65 + hr];
        o.z = tl[(lc * 4 + 2) * 65 + hr];
        o.w = tl[(lc * 4 + 3) * 65 + hr];
        *(float4*)(dst + ((size_t)(b * Hn + h0 + hr)) * Ln + l0 + lc * 4) = o;
    }
}

// ---------------------------------------------------------------------------
// t16: yT (b, 256, 4096) bf16 -> yN (b, 4096, 256) bf16.  64x64 LDS tile.
// ---------------------------------------------------------------------------
__global__ __launch_bounds__(256) void t16_kernel(
    const unsigned short* __restrict__ src, unsigned short* __restrict__ dst)
{
    __shared__ unsigned short tl[64 * 66];
    const int tid = threadIdx.x;
    const int l0 = blockIdx.x * 64, h0 = blockIdx.y * 64, b = blockIdx.z;
    #pragma unroll
    for (int it = 0; it < 2; ++it) {
        int idx = it * 256 + tid; int r = idx >> 3, c8 = idx & 7;   // r = h-row
        uint4 g = *(const uint4*)(src + ((size_t)(b * Hn + h0 + r)) * Ln + l0 + c8 * 8);
        unsigned short* p = &tl[r * 66 + c8 * 8];
        p[0] = g.x & 0xffff; p[1] = g.x >> 16;
        p[2] = g.y & 0xffff; p[3] = g.y >> 16;
        p[4] = g.z & 0xffff; p[5] = g.z >> 16;
        p[6] = g.w & 0xffff; p[7] = g.w >> 16;
    }
    __syncthreads();
    #pragma unroll
    for (int it = 0; it < 2; ++it) {
        int idx = it * 256 + tid; int hc = idx & 7, lr = idx >> 3;  // lr 0..63
        unsigned short e[8];
        #pragma unroll
        for (int j = 0; j < 8; ++j) e[j] = tl[(hc * 8 + j) * 66 + lr];
        uint4 o;
        o.x = (unsigned)e[0] | ((unsigned)e[1] << 16);
        o.y = (unsigned)e[2] | ((unsigned)e[3] << 16);
        o.z = (unsigned)e[4] | ((unsigned)e[5] << 16);
        o.w = (unsigned)e[6] | ((unsigned)e[7] << 16);
        *(uint4*)(dst + ((size_t)(b * Ln + l0 + lr)) * Hn + h0 + hc * 8) = o;
    }
}

// ---------------------------------------------------------------------------
// MFMA GEMM: C(M,256) = A(M,KDIM) @ W(Nrows,KDIM)^T (+bias, +GLU, +resid)
// 128x64 block tile, BK=64, 4 waves (2x2), mfma_f32_16x16x32_bf16.
// A: bf16 row-major (or f32 converted in-flight when ACVT).
// W: f32, converted to bf16 during staging.  GLU: g-rows at W + 256*KDIM.
// LDS rows padded to 72 bf16 (144 B) -> uniform bank groups for b128 ops.
// ---------------------------------------------------------------------------
template<int KDIM, bool GLU, bool ACVT>
__global__ __launch_bounds__(256) void mfma_gemm(
    const unsigned short* __restrict__ Abf,
    const float* __restrict__ Af,
    const float* __restrict__ W,
    const float* __restrict__ ba,
    const float* __restrict__ bg,
    const float* resid,              // aliases Hout (read-before-write, block-owned)
    float* Hout)
{
    __shared__ unsigned short As[128 * 72];
    __shared__ unsigned short Bs[2][64 * 72];

    const int tid = threadIdx.x;
    const int lane = tid & 63, w = tid >> 6;
    const int wm = w >> 1, wn = w & 1;
    const int lr = lane & 15, lq = lane >> 4;
    const int row0 = blockIdx.x * 128;
    const int n0 = blockIdx.y * 64;

    f32x4 accA[4][2], accG[4][2];
    #pragma unroll
    for (int i = 0; i < 4; ++i)
        #pragma unroll
        for (int j = 0; j < 2; ++j) {
            accA[i][j] = (f32x4)0.0f;
            accG[i][j] = (f32x4)0.0f;
        }

    for (int kt = 0; kt < KDIM / 64; ++kt) {
        const int k0 = kt * 64;
        // ---- stage A (128 rows x 64 k) ----
        #pragma unroll
        for (int it = 0; it < 4; ++it) {
            int idx = it * 256 + tid; int m = idx >> 3, q = idx & 7;
            uint4 v;
            if constexpr (ACVT) {
                const float* s = Af + (size_t)(row0 + m) * KDIM + k0 + q * 8;
                float4 g1 = *(const float4*)s;
                float4 g2 = *(const float4*)(s + 4);
                v = pack8(g1, g2);
            } else {
                v = *(const uint4*)(Abf + (size_t)(row0 + m) * KDIM + k0 + q * 8);
            }
            *(uint4*)(&As[m * 72 + q * 8]) = v;
        }
        // ---- stage B (64 rows x 64 k, f32 -> bf16) ----
        #pragma unroll
        for (int it = 0; it < 2; ++it) {
            int idx = it * 256 + tid; int p = idx >> 3, q = idx & 7;
            {
                const float* s = W + (size_t)(n0 + p) * KDIM + k0 + q * 8;
                float4 g1 = *(const float4*)s;
                float4 g2 = *(const float4*)(s + 4);
                *(uint4*)(&Bs[0][p * 72 + q * 8]) = pack8(g1, g2);
            }
            if constexpr (GLU) {
                const float* s = W + (size_t)(256 + n0 + p) * KDIM + k0 + q * 8;
                float4 g1 = *(const float4*)s;
                float4 g2 = *(const float4*)(s + 4);
                *(uint4*)(&Bs[1][p * 72 + q * 8]) = pack8(g1, g2);
            }
        }
        __syncthreads();
        // ---- MFMA ----
        #pragma unroll
        for (int kf = 0; kf < 2; ++kf) {
            bf16x8 av[4], bv[2], gv[2];
            #pragma unroll
            for (int mf = 0; mf < 4; ++mf)
                av[mf] = *(const bf16x8*)(&As[(wm * 64 + mf * 16 + lr) * 72 + (kf * 4 + lq) * 8]);
            #pragma unroll
            for (int nf = 0; nf < 2; ++nf) {
                bv[nf] = *(const bf16x8*)(&Bs[0][(wn * 32 + nf * 16 + lr) * 72 + (kf * 4 + lq) * 8]);
                if constexpr (GLU)
                    gv[nf] = *(const bf16x8*)(&Bs[1][(wn * 32 + nf * 16 + lr) * 72 + (kf * 4 + lq) * 8]);
            }
            #pragma unroll
            for (int mf = 0; mf < 4; ++mf)
                #pragma unroll
                for (int nf = 0; nf < 2; ++nf) {
                    accA[mf][nf] = __builtin_amdgcn_mfma_f32_16x16x32_bf16(av[mf], bv[nf], accA[mf][nf], 0, 0, 0);
                    if constexpr (GLU)
                        accG[mf][nf] = __builtin_amdgcn_mfma_f32_16x16x32_bf16(av[mf], gv[nf], accG[mf][nf], 0, 0, 0);
                }
        }
        __syncthreads();
    }

    // ---- epilogue: bias (+GLU +resid), scalar stores ----
    int pc[2]; float bA[2], bG[2];
    #pragma unroll
    for (int nf = 0; nf < 2; ++nf) {
        pc[nf] = n0 + wn * 32 + nf * 16 + lr;
        bA[nf] = ba[pc[nf]];
        if constexpr (GLU) bG[nf] = bg[pc[nf]];
    }
    #pragma unroll
    for (int mf = 0; mf < 4; ++mf) {
        #pragma unroll
        for (int r = 0; r < 4; ++r) {
            size_t rbase = (size_t)(row0 + wm * 64 + mf * 16 + lq * 4 + r) * Hn;
            #pragma unroll
            for (int nf = 0; nf < 2; ++nf) {
                float o;
                if constexpr (GLU) {
                    float aval = accA[mf][nf][r] + bA[nf];
                    float gval = accG[mf][nf][r] + bG[nf];
                    o = aval * sigmoid_f(gval) + resid[rbase + pc[nf]];
                } else {
                    o = accA[mf][nf][r] + bA[nf];
                }
                Hout[rbase + pc[nf]] = o;
            }
        }
    }
}

extern "C" void kernel_launch(void* const* d_in, const int* in_sizes, int n_in,
                              void* d_out, int out_size, void* d_ws, size_t ws_size,
                              hipStream_t stream) {
    (void)in_sizes; (void)n_in; (void)out_size; (void)ws_size;
    const float* x          = (const float*)d_in[0];
    const float* enc_w      = (const float*)d_in[1];
    const float* enc_b      = (const float*)d_in[2];
    const float* log_dt     = (const float*)d_in[3];
    const float* log_A_real = (const float*)d_in[4];
    const float* A_imag     = (const float*)d_in[5];
    const float* C_re       = (const float*)d_in[6];
    const float* C_im       = (const float*)d_in[7];
    const float* D_skip     = (const float*)d_in[8];
    const float* out_w      = (const float*)d_in[9];
    const float* out_b      = (const float*)d_in[10];

    const size_t NE = (size_t)Bn * Hn * Ln;           // 8388608
    float* h  = (float*)d_out;                        // (B,L,H) residual stream
    float* hT = (float*)d_ws;                         // (B,H,L) f32
    unsigned short* yT = (unsigned short*)(hT + NE);  // (B,H,L) bf16
    unsigned short* yN = yT + NE;                     // (B,L,H) bf16

    const dim3 gb(256);

    // encoder: h = x @ enc_w^T + enc_b  (bf16 MFMA, f32 conv in staging)
    mfma_gemm<DINn, false, true><<<dim3(256, 4), gb, 0, stream>>>(
        nullptr, x, enc_w, enc_b, nullptr, nullptr, h);

    for (int i = 0; i < NLn; ++i) {
        t32_kernel<<<dim3(64, 4, 8), gb, 0, stream>>>(h, hT);
        s4_scan_kernel<<<dim3(Hn / 4, Bn), gb, 0, stream>>>(
            hT, yT,
            log_dt + (size_t)i * Hn,
            log_A_real + (size_t)i * Hn * N2n,
            A_imag + (size_t)i * Hn * N2n,
            C_re + (size_t)i * Hn * N2n,
            C_im + (size_t)i * Hn * N2n,
            D_skip + (size_t)i * Hn);
        t16_kernel<<<dim3(64, 4, 8), gb, 0, stream>>>(yT, yN);
        mfma_gemm<Hn, true, false><<<dim3(256, 4), gb, 0, stream>>>(
            yN, nullptr, out_w + (size_t)i * 2 * Hn * Hn,
            out_b + (size_t)i * 2 * Hn, out_b + (size_t)i * 2 * Hn + Hn,
            h, h);
    }
}